// Round 2
// 242.973 us; speedup vs baseline: 1.0369x; 1.0369x over previous
//
#include <hip/hip_runtime.h>
#include <math.h>

#define TAU_F 32.0f

typedef __attribute__((ext_vector_type(8))) _Float16 half8;
typedef __attribute__((ext_vector_type(2))) __fp16 half2v;
typedef __attribute__((ext_vector_type(4))) float f32x4;

union HU { uint4 u; half8 v; };

__device__ __forceinline__ void sync_lds_only() {
    // CK-style block_sync_lds: drain LDS ops, leave VMEM (vmcnt) in flight.
    asm volatile("s_waitcnt lgkmcnt(0)" ::: "memory");
    __builtin_amdgcn_s_barrier();
}

// ============ Kernel 1: G partials, fp32 VALU, no atomics (unchanged) ============
// P[ks][192][2048], ks=4. Rows: 0..89 topic, 90..95 zero, 96..185 domain, 186..191 zero.
__global__ __launch_bounds__(256) void gproj2(
    const float* __restrict__ Wt, const float* __restrict__ Wd,
    const float* __restrict__ mem, const int* __restrict__ cat,
    float* __restrict__ P)
{
    __shared__ float Ml[96 * 36];
    __shared__ float Wl[32 * 68];

    const int bid = blockIdx.x;
    const int mat = bid >> 7;
    const int ks  = (bid >> 5) & 3;
    const int ct  = bid & 31;
    const int c0  = ct * 64;
    const int tid = threadIdx.x;
    const float* __restrict__ W = mat ? Wd : Wt;

    const int tr = tid >> 4;
    const int tc = tid & 15;

    float acc[6][4];
    #pragma unroll
    for (int j = 0; j < 6; ++j)
        #pragma unroll
        for (int q = 0; q < 4; ++q) acc[j][q] = 0.f;

    for (int ch = 0; ch < 6; ++ch) {
        __syncthreads();
        #pragma unroll
        for (int p = 0; p < 3; ++p) {
            const int idx = tid + 256 * p;
            const int r   = idx >> 3;
            const int kq  = idx & 7;
            float4 v = make_float4(0.f, 0.f, 0.f, 0.f);
            if (r < 90) {
                const int d = r / 10;
                const int mrow = cat[d] * 10 + (r - d * 10);
                v = *(const float4*)(mem + (size_t)mrow * 768 + ks * 192 + ch * 32 + kq * 4);
            }
            *(float4*)(Ml + r * 36 + kq * 4) = v;
        }
        #pragma unroll
        for (int p = 0; p < 2; ++p) {
            const int idx = tid + 256 * p;
            const int e   = idx >> 4;
            const int c4  = (idx & 15) * 4;
            *(float4*)(Wl + e * 68 + c4) =
                *(const float4*)(W + (size_t)(ks * 192 + ch * 32 + e) * 2048 + c0 + c4);
        }
        __syncthreads();

        #pragma unroll
        for (int e = 0; e < 32; e += 4) {
            float4 m4[6], w4[4];
            #pragma unroll
            for (int j = 0; j < 6; ++j) m4[j] = *(const float4*)(Ml + (tr * 6 + j) * 36 + e);
            #pragma unroll
            for (int q = 0; q < 4; ++q) w4[q] = *(const float4*)(Wl + (e + q) * 68 + tc * 4);
            #pragma unroll
            for (int j = 0; j < 6; ++j) {
                const float mv[4] = {m4[j].x, m4[j].y, m4[j].z, m4[j].w};
                #pragma unroll
                for (int q = 0; q < 4; ++q) {
                    acc[j][0] = fmaf(mv[q], w4[q].x, acc[j][0]);
                    acc[j][1] = fmaf(mv[q], w4[q].y, acc[j][1]);
                    acc[j][2] = fmaf(mv[q], w4[q].z, acc[j][2]);
                    acc[j][3] = fmaf(mv[q], w4[q].w, acc[j][3]);
                }
            }
        }
    }

    #pragma unroll
    for (int j = 0; j < 6; ++j) {
        float4 v = make_float4(acc[j][0], acc[j][1], acc[j][2], acc[j][3]);
        *(float4*)(P + (size_t)ks * 393216 + (size_t)(mat * 96 + tr * 6 + j) * 2048 + c0 + tc * 4) = v;
    }
}

// ============ Kernel 2: reduce partials -> f16 hi/lo, fragment-major (unchanged) ============
// frag f = (kc*12 + nq*3 + j)*2 + plane; addr = f*512 + lq*128 + lm*8
__global__ __launch_bounds__(256) void split_g3(
    const float* __restrict__ P, unsigned short* __restrict__ gB)
{
    const int u  = blockIdx.x * 256 + threadIdx.x;  // 0..49151
    const int n  = u >> 8;                          // 0..191
    const int k0 = (u & 255) * 8;                   // 0..2040

    float s[8] = {0.f, 0.f, 0.f, 0.f, 0.f, 0.f, 0.f, 0.f};
    #pragma unroll
    for (int ks = 0; ks < 4; ++ks) {
        const float4 a = *(const float4*)(P + (size_t)ks * 393216 + (size_t)n * 2048 + k0);
        const float4 b = *(const float4*)(P + (size_t)ks * 393216 + (size_t)n * 2048 + k0 + 4);
        s[0] += a.x; s[1] += a.y; s[2] += a.z; s[3] += a.w;
        s[4] += b.x; s[5] += b.y; s[6] += b.z; s[7] += b.w;
    }
    union { _Float16 h[8]; uint4 u4; } hi, lo;
    #pragma unroll
    for (int e = 0; e < 8; ++e) {
        const _Float16 h = (_Float16)s[e];   // RNE
        hi.h[e] = h;
        lo.h[e] = (_Float16)(s[e] - (float)h);
    }
    const int kc = k0 >> 5;
    const int lq = (k0 >> 3) & 3;
    const int nq = n / 48;
    const int rm = n - nq * 48;
    const int j  = rm >> 4;
    const int lm = rm & 15;
    const size_t fH = (size_t)((kc * 12 + nq * 3 + j) * 2 + 0) * 512 + lq * 128 + lm * 8;
    const size_t fL = (size_t)((kc * 12 + nq * 3 + j) * 2 + 1) * 512 + lq * 128 + lm * 8;
    *(uint4*)(gB + fH) = hi.u4;
    *(uint4*)(gB + fL) = lo.u4;
}

// ============ Kernel 3: full-K split-f16 MFMA GEMM + fused softmax epilogue ============
// 512 blocks = row-tiles of 32, full K=2048 per block (no K-split -> no P2/ssqp/ep_kernel).
// 256 thr = 4 waves; role nq=(w+bid)&3: nq<2 topic cols (3-pass), nq>=2 domain (1-pass).
// Main-loop barriers are lgkmcnt-only; global prefetch (A) rides through; B is L2-resident.
__global__ __launch_bounds__(256, 2) void fused_ep(
    const float* __restrict__ feat, const unsigned short* __restrict__ gB,
    float* __restrict__ out)
{
    // LDS: A-staging (split-f16, double-buffered) then REUSED as the 32x192 score panel.
    // aS: [buf2][plane2][kf2][row32][40]  (40-half rows: 16B-aligned b128, 2-way banks = free)
    // sc: [row32][193]                    (193-word stride: conflict-free per-row epilogue reads)
    __shared__ __align__(16) unsigned char smraw[32 * 193 * 4];
    unsigned short* aS = (unsigned short*)smraw;
    float* sc = (float*)smraw;
    __shared__ float ssqS[32];

    const int tid  = threadIdx.x;
    const int row0 = blockIdx.x * 32;

    const int w  = tid >> 6, l = tid & 63;
    const int lm = l & 15,  lq = l >> 4;
    const int nq = (w + blockIdx.x) & 3;     // role rotation balances SIMDs across blocks
    const bool topic = (nq < 2);
    const int sr = tid >> 3, kq = tid & 7;   // staging: row 0..31, k-octet 0..7 (64 K / step)
    const int skf = kq >> 2, sk4 = kq & 3;

    f32x4 acc[2][3];
    #pragma unroll
    for (int i = 0; i < 2; ++i)
        #pragma unroll
        for (int j = 0; j < 3; ++j) acc[i][j] = (f32x4)0.f;
    float ssq = 0.f;

    const float* fbase = feat + (size_t)(row0 + sr) * 2048 + kq * 8;
    const unsigned short* bbase = gB + nq * 3072 + l * 8;

    // convert+stage helper (fp32 -> f16 hi/lo planes, fused ssq)
    auto cw = [&](int buf, float4 va, float4 vb) {
        const float xs[8] = {va.x, va.y, va.z, va.w, vb.x, vb.y, vb.z, vb.w};
        union { half2v h2[4]; uint4 u4; } uh, ul;
        #pragma unroll
        for (int e = 0; e < 4; ++e) {
            const float a = xs[2 * e], b = xs[2 * e + 1];
            ssq = fmaf(a, a, ssq); ssq = fmaf(b, b, ssq);
            half2v h = __builtin_amdgcn_cvt_pkrtz(a, b);
            uh.h2[e] = h;
            ul.h2[e] = __builtin_amdgcn_cvt_pkrtz(a - (float)h[0], b - (float)h[1]);
        }
        *(uint4*)(aS + (size_t)(((buf * 2 + 0) * 2 + skf) * 32 + sr) * 40 + sk4 * 8) = uh.u4;
        *(uint4*)(aS + (size_t)(((buf * 2 + 1) * 2 + skf) * 32 + sr) * 40 + sk4 * 8) = ul.u4;
    };

    // ---- prologue: A steps 0,1 into regs; stage step 0 ----
    float4 c0a = *(const float4*)(fbase);
    float4 c0b = *(const float4*)(fbase + 4);
    float4 c1a = *(const float4*)(fbase + 64);
    float4 c1b = *(const float4*)(fbase + 68);
    cw(0, c0a, c0b);
    sync_lds_only();

    for (int kt = 0; kt < 32; ++kt) {
        // B for THIS step (gB is 1.57 MB -> L2-resident; latency hidden under cw + ds_reads)
        uint4 bh[6], bl[6];
        #pragma unroll
        for (int kf = 0; kf < 2; ++kf)
            #pragma unroll
            for (int j = 0; j < 3; ++j)
                bh[kf * 3 + j] = *(const uint4*)(bbase + (size_t)(2 * kt + kf) * 12288 + j * 1024);
        if (topic) {
            #pragma unroll
            for (int kf = 0; kf < 2; ++kf)
                #pragma unroll
                for (int j = 0; j < 3; ++j)
                    bl[kf * 3 + j] = *(const uint4*)(bbase + (size_t)(2 * kt + kf) * 12288 + j * 1024 + 512);
        }
        // A prefetch for step kt+2 (rides through the barrier; never drained)
        const int ka = (kt + 2 < 32) ? kt + 2 : 31;
        float4 cna = *(const float4*)(fbase + ka * 64);
        float4 cnb = *(const float4*)(fbase + ka * 64 + 4);

        // stage step kt+1 into the other buffer (no race with this-step reads)
        if (kt < 31) cw((kt + 1) & 1, c1a, c1b);

        // A fragments from buf kt&1
        const int cb = kt & 1;
        half8 fh[2][2], fl[2][2];
        #pragma unroll
        for (int i = 0; i < 2; ++i)
            #pragma unroll
            for (int kf = 0; kf < 2; ++kf) {
                HU t;
                t.u = *(const uint4*)(aS + (size_t)(((cb * 2 + 0) * 2 + kf) * 32 + i * 16 + lm) * 40 + lq * 8);
                fh[i][kf] = t.v;
            }
        if (topic) {
            #pragma unroll
            for (int i = 0; i < 2; ++i)
                #pragma unroll
                for (int kf = 0; kf < 2; ++kf) {
                    HU t;
                    t.u = *(const uint4*)(aS + (size_t)(((cb * 2 + 1) * 2 + kf) * 32 + i * 16 + lm) * 40 + lq * 8);
                    fl[i][kf] = t.v;
                }
        }

        if (topic) {
            #pragma unroll
            for (int j = 0; j < 3; ++j)
                #pragma unroll
                for (int kf = 0; kf < 2; ++kf) {
                    HU h8, l8; h8.u = bh[kf * 3 + j]; l8.u = bl[kf * 3 + j];
                    #pragma unroll
                    for (int i = 0; i < 2; ++i) {
                        acc[i][j] = __builtin_amdgcn_mfma_f32_16x16x32_f16(fh[i][kf], h8.v, acc[i][j], 0, 0, 0);
                        acc[i][j] = __builtin_amdgcn_mfma_f32_16x16x32_f16(fh[i][kf], l8.v, acc[i][j], 0, 0, 0);
                        acc[i][j] = __builtin_amdgcn_mfma_f32_16x16x32_f16(fl[i][kf], h8.v, acc[i][j], 0, 0, 0);
                    }
                }
        } else {
            #pragma unroll
            for (int j = 0; j < 3; ++j)
                #pragma unroll
                for (int kf = 0; kf < 2; ++kf) {
                    HU h8; h8.u = bh[kf * 3 + j];
                    #pragma unroll
                    for (int i = 0; i < 2; ++i)
                        acc[i][j] = __builtin_amdgcn_mfma_f32_16x16x32_f16(fh[i][kf], h8.v, acc[i][j], 0, 0, 0);
                }
        }

        sync_lds_only();   // lgkm drain + barrier only — vmcnt prefetch stays in flight
        c1a = cna; c1b = cnb;
    }

    // ---- scores -> LDS (overwrites aS; safe: last barrier drained all A-frag reads) ----
    #pragma unroll
    for (int i = 0; i < 2; ++i)
        #pragma unroll
        for (int j = 0; j < 3; ++j)
            #pragma unroll
            for (int r4 = 0; r4 < 4; ++r4)
                sc[(i * 16 + lq * 4 + r4) * 193 + nq * 48 + j * 16 + lm] = acc[i][j][r4];

    // ssq: 8 staging threads per row (kq 0..7) -> full-row |feat|^2
    ssq += __shfl_xor(ssq, 1, 64);
    ssq += __shfl_xor(ssq, 2, 64);
    ssq += __shfl_xor(ssq, 4, 64);
    if (kq == 0) ssqS[sr] = ssq;
    __syncthreads();

    // ---- softmax epilogue: 2 lanes per row (domains 0..4 / 5..8), wave 0 only ----
    if (tid < 64) {
        const int r  = tid >> 1, hf = tid & 1;
        const int nd = hf ? 4 : 5;
        const int d0 = hf ? 5 : 0;
        const float inv = TAU_F / fmaxf(sqrtf(ssqS[r]), 1e-12f);
        const float* scr = sc + (size_t)r * 193;
        float lg[5];
        float dmax = -1e30f;
        #pragma unroll
        for (int dd = 0; dd < 5; ++dd) {
            if (dd < nd) {
                const int d = d0 + dd;
                const float* v = scr + d * 10;          // topic cols 0..89
                const float* u = scr + 96 + d * 10;     // domain cols 96..185
                float mx = v[0];
                #pragma unroll
                for (int m = 1; m < 10; ++m) mx = fmaxf(mx, v[m]);
                float ssum = 0.f, dot = 0.f;
                #pragma unroll
                for (int m = 0; m < 10; ++m) {
                    const float p = __expf((v[m] - mx) * inv);
                    ssum += p;
                    dot = fmaf(p, u[m], dot);
                }
                const float lgt = (dot / ssum) * inv;
                lg[dd] = lgt;
                dmax = fmaxf(dmax, lgt);
            } else {
                lg[dd] = -1e30f;                        // exp -> 0, doesn't affect sums
            }
        }
        dmax = fmaxf(dmax, __shfl_xor(dmax, 1, 64));
        float s2 = 0.f;
        #pragma unroll
        for (int dd = 0; dd < 5; ++dd) {
            const float p = __expf(lg[dd] - dmax);
            lg[dd] = p;
            s2 += p;
        }
        s2 += __shfl_xor(s2, 1, 64);
        const float r2 = 1.0f / s2;
        #pragma unroll
        for (int dd = 0; dd < 5; ++dd)
            if (dd < nd)
                out[(size_t)(row0 + r) * 9 + d0 + dd] = lg[dd] * r2;
    }
}

extern "C" void kernel_launch(void* const* d_in, const int* in_sizes, int n_in,
                              void* d_out, int out_size, void* d_ws, size_t ws_size,
                              hipStream_t stream) {
    const float* feature = (const float*)d_in[0];
    const float* Wt      = (const float*)d_in[1];
    const float* Wd      = (const float*)d_in[2];
    const float* mem     = (const float*)d_in[3];
    const int*   cat     = (const int*)d_in[4];

    // ws layout: P (6.3 MB) | gB 1.57 MB @50331648 (P2/ssqp eliminated by full-K fusion)
    float* P  = (float*)d_ws;
    unsigned short* gB = (unsigned short*)((char*)d_ws + 50331648);
    float* out = (float*)d_out;

    gproj2<<<256, 256, 0, stream>>>(Wt, Wd, mem, cat, P);
    split_g3<<<192, 256, 0, stream>>>(P, gB);
    fused_ep<<<512, 256, 0, stream>>>(feature, gB, out);
}